// Round 1
// baseline (5080.214 us; speedup 1.0000x reference)
//
#include <hip/hip_runtime.h>
#include <stdint.h>

#define NB    4
#define CIN   128
#define TQ    256
#define TS    257
#define TD    65
#define NPIX  (TQ*TD)     /* 16640 */
#define COUT  512
#define HID   256
#define SPAD  264
#define DCHUNK 22

// ---------------- bf16 helpers ----------------
__device__ __forceinline__ float bf2f(unsigned short u) {
    union { unsigned int i; float f; } v; v.i = ((unsigned int)u) << 16; return v.f;
}
__device__ __forceinline__ unsigned short f2bf(float x) {
    union { float f; unsigned int i; } v; v.f = x;
    unsigned int r = v.i + 0x7fffu + ((v.i >> 16) & 1u);
    return (unsigned short)(r >> 16);
}
__device__ __forceinline__ void bfp2(unsigned int u, float& a, float& b) {
    union { unsigned int i; float f; } x, y;
    x.i = u << 16; y.i = u & 0xffff0000u;
    a = x.f; b = y.f;
}
__device__ __forceinline__ void unpack8(uint4 v, float (&f)[8]) {
    bfp2(v.x, f[0], f[1]); bfp2(v.y, f[2], f[3]);
    bfp2(v.z, f[4], f[5]); bfp2(v.w, f[6], f[7]);
}

// ---------------- mask: exact gather (linspace step = 17, frac = 0) ----------------
__global__ void mask_kernel(const int* __restrict__ sm, float* __restrict__ m16) {
    int b = blockIdx.x; int t = threadIdx.x;           // 256 threads
    int i = t >> 4, j = t & 15;
    int v = sm[(size_t)b * 65536 + i * 17 * 256 + j * 17];
    m16[b * 256 + t] = (v != 0) ? 1.0f : 0.0f;
}

// ---------------- cst_pool on corr ----------------
__global__ void pool_kernel(const float* __restrict__ corr, float* __restrict__ corrp) {
    size_t total = (size_t)NB * CIN * TQ * TD;
    for (size_t idx = (size_t)blockIdx.x * blockDim.x + threadIdx.x; idx < total;
         idx += (size_t)gridDim.x * blockDim.x) {
        int d = (int)(idx % TD);
        size_t rest = idx / TD;                        // (b*C + c)*TQ + q
        const float* src = corr + rest * TS;
        float val;
        if (d == 0) val = src[0];
        else {
            int dd = d - 1; int i = dd >> 3, j = dd & 7;
            int s = 1 + i * 32 + j * 2;
            val = 0.25f * (src[s] + src[s + 1] + src[s + 16] + src[s + 17]);
        }
        corrp[idx] = val;
    }
}

// ---------------- group-norm stats (sum, sumsq) per contiguous (b,g) span ----------------
__global__ void stats_kernel(const float* __restrict__ x, float* __restrict__ st, int Cg) {
    size_t len = (size_t)Cg * NPIX;
    size_t base = (size_t)blockIdx.y * len;
    const float4* x4 = reinterpret_cast<const float4*>(x + base);
    size_t len4 = len >> 2;
    float s = 0.f, ss = 0.f;
    for (size_t i = (size_t)blockIdx.x * blockDim.x + threadIdx.x; i < len4;
         i += (size_t)gridDim.x * blockDim.x) {
        float4 v = x4[i];
        s  += v.x + v.y + v.z + v.w;
        ss += v.x * v.x + v.y * v.y + v.z * v.z + v.w * v.w;
    }
    #pragma unroll
    for (int o = 32; o > 0; o >>= 1) { s += __shfl_down(s, o, 64); ss += __shfl_down(ss, o, 64); }
    __shared__ float red[4][2];
    int wid = threadIdx.x >> 6, lane = threadIdx.x & 63;
    if (lane == 0) { red[wid][0] = s; red[wid][1] = ss; }
    __syncthreads();
    if (threadIdx.x == 0) {
        float S  = red[0][0] + red[1][0] + red[2][0] + red[3][0];
        float SS = red[0][1] + red[1][1] + red[2][1] + red[3][1];
        atomicAdd(&st[blockIdx.y * 2],     S);
        atomicAdd(&st[blockIdx.y * 2 + 1], SS);
    }
}

__device__ __forceinline__ float2 gn_params(const float* st, int bg, float invcnt) {
    float mu  = st[bg * 2] * invcnt;
    float var = st[bg * 2 + 1] * invcnt - mu * mu;
    float2 r; r.x = mu; r.y = rsqrtf(var + 1e-5f); return r;
}

// ---------------- tiled fp32 GEMM: Y(b,m,n) = sum_k W(m,k) X(b,k,n) ----------------
// MODE 0: plain   MODE 1: + bias[m] on output   MODE 2: gn+relu transform on X
template<int MODE>
__global__ __launch_bounds__(256) void gemm_kernel(
    const float* __restrict__ W, const float* __restrict__ X, float* __restrict__ Y,
    int M, int K,
    const float* __restrict__ bias,
    const float* __restrict__ stats, const float* __restrict__ gw, const float* __restrict__ gb,
    int Cg, float invcnt)
{
    const int N = NPIX;
    int b  = blockIdx.z;
    int m0 = blockIdx.y * 64;
    int n0 = blockIdx.x * 64;
    __shared__ float sA[16][68];   // [k][m]
    __shared__ float sB[16][68];   // [k][n]
    int t = threadIdx.x;
    int tr = t >> 4, tc = t & 15;
    float acc[4][4] = {};
    const float* Xb = X + (size_t)b * K * N;
    for (int k0 = 0; k0 < K; k0 += 16) {
        {   // W tile 64m x 16k
            int r = t >> 4, c = t & 15;
            #pragma unroll
            for (int i = 0; i < 4; i++) {
                int m = m0 + r + i * 16;
                sA[c][r + i * 16] = W[(size_t)m * K + k0 + c];
            }
        }
        {   // X tile 16k x 64n (+transform)
            int r = t >> 6, c = t & 63;
            #pragma unroll
            for (int i = 0; i < 4; i++) {
                int k = k0 + r + i * 4;
                float v = Xb[(size_t)k * N + n0 + c];
                if (MODE == 2) {
                    int g = k / Cg;
                    float2 p = gn_params(stats, b * 4 + g, invcnt);
                    v = (v - p.x) * p.y * gw[k] + gb[k];
                    v = fmaxf(v, 0.0f);
                }
                sB[r + i * 4][c] = v;
            }
        }
        __syncthreads();
        #pragma unroll
        for (int kk = 0; kk < 16; kk++) {
            float4 a4 = *reinterpret_cast<const float4*>(&sA[kk][tr * 4]);
            float4 b4 = *reinterpret_cast<const float4*>(&sB[kk][tc * 4]);
            float av[4] = {a4.x, a4.y, a4.z, a4.w};
            float bv[4] = {b4.x, b4.y, b4.z, b4.w};
            #pragma unroll
            for (int i = 0; i < 4; i++)
                #pragma unroll
                for (int j = 0; j < 4; j++)
                    acc[i][j] += av[i] * bv[j];
        }
        __syncthreads();
    }
    #pragma unroll
    for (int i = 0; i < 4; i++) {
        int m = m0 + tr * 4 + i;
        float bs = (MODE == 1) ? bias[m] : 0.0f;
        float4 r;
        r.x = acc[i][0] + bs; r.y = acc[i][1] + bs; r.z = acc[i][2] + bs; r.w = acc[i][3] + bs;
        *reinterpret_cast<float4*>(&Y[((size_t)b * M + m) * N + n0 + tc * 4]) = r;
    }
}

// ---------------- fused attention: K/V proj + QK^T + mask + softmax + PV ----------------
__global__ __launch_bounds__(320) void attn_kernel(
    const float* __restrict__ corr,   // (B,128,TQ,TS)
    const float* __restrict__ Wqkv,   // (768,128)
    const float* __restrict__ bqkv,   // (768)
    const float* __restrict__ qp,     // (B,256,TQ,TD)
    const float* __restrict__ m16,    // (B,256)
    float* __restrict__ att)          // (B,256,TQ,TD)
{
    int g = blockIdx.x, q = blockIdx.y, b = blockIdx.z;
    int t = threadIdx.x;

    __shared__ unsigned short sK[SPAD * 32];     // [s][e] bf16
    __shared__ unsigned short sV[SPAD * 32];     // [s][e] bf16
    __shared__ unsigned short sQ[65 * 32];       // [d][e] bf16
    __shared__ union {
        struct { unsigned short W[128 * 64]; unsigned short X[16 * SPAD]; } p1;
        float S[DCHUNK * SPAD];
    } u;

    // stage W (transposed [c][r], r<32: K-row, r>=32: V-row)
    for (int idx = t; idx < 128 * 64; idx += 320) {
        int r = idx >> 7, c = idx & 127;
        int row = (r < 32) ? (HID + g * 32 + r) : (2 * HID + g * 32 + (r - 32));
        u.p1.W[c * 64 + r] = f2bf(Wqkv[(size_t)row * 128 + c]);
    }
    // stage Q tile [d][e]
    for (int idx = t; idx < 65 * 32; idx += 320) {
        int e = idx / 65, d = idx % 65;
        sQ[d * 32 + e] = f2bf(qp[(((size_t)b * HID + g * 32 + e) * TQ + q) * TD + d]);
    }

    const float* corr_bq = corr + (size_t)b * CIN * TQ * TS + (size_t)q * TS;

    // ---- P1a: K/V = W * x, 8x8 register tiles ----
    int tc = t % 40, tr = t / 40;     // 40 col-groups (33 active), 8 row-groups
    int s0 = tc * 8, r0 = tr * 8;
    float acc[8][8] = {};
    for (int c0 = 0; c0 < 128; c0 += 16) {
        for (int idx = t; idx < 16 * SPAD; idx += 320) {
            int cc = idx / SPAD, s2 = idx % SPAD;
            float v = (s2 < TS) ? corr_bq[(size_t)(c0 + cc) * (TQ * TS) + s2] : 0.0f;
            u.p1.X[cc * SPAD + s2] = f2bf(v);
        }
        __syncthreads();
        if (tc < 33) {
            #pragma unroll 4
            for (int cc = 0; cc < 16; cc++) {
                uint4 wv = *reinterpret_cast<const uint4*>(&u.p1.W[(c0 + cc) * 64 + r0]);
                uint4 xv = *reinterpret_cast<const uint4*>(&u.p1.X[cc * SPAD + s0]);
                float wf[8], xf[8];
                unpack8(wv, wf); unpack8(xv, xf);
                #pragma unroll
                for (int i = 0; i < 8; i++)
                    #pragma unroll
                    for (int j = 0; j < 8; j++)
                        acc[i][j] += wf[i] * xf[j];
            }
        }
        __syncthreads();
    }
    // write K/V (+bias) to LDS
    if (tc < 33) {
        int e0   = (tr < 4) ? r0 : (r0 - 32);
        int boff = (tr < 4) ? (HID + g * 32) : (2 * HID + g * 32);
        unsigned short* dst = (tr < 4) ? sK : sV;
        float bias_[8];
        #pragma unroll
        for (int i = 0; i < 8; i++) bias_[i] = bqkv[boff + e0 + i];
        #pragma unroll
        for (int j = 0; j < 8; j++) {
            int s = s0 + j;
            union { unsigned short us[8]; uint4 v4; } tmp;
            #pragma unroll
            for (int i = 0; i < 8; i++) tmp.us[i] = f2bf(acc[i][j] + bias_[i]);
            *reinterpret_cast<uint4*>(&dst[s * 32 + e0]) = tmp.v4;
        }
    }
    __syncthreads();

    // ---- per-column state for scores ----
    bool colact = (t < SPAD);
    bool masked = false;
    if (colact) {
        if (t >= TS) masked = true;                                    // padding cols
        else if (t >= 1) masked = (m16[b * 256 + t - 1] == 0.0f);
    }
    float kcol[32];
    if (colact) {
        const uint4* kp = reinterpret_cast<const uint4*>(&sK[t * 32]);
        float f0[8], f1[8], f2[8], f3[8];
        unpack8(kp[0], f0); unpack8(kp[1], f1); unpack8(kp[2], f2); unpack8(kp[3], f3);
        #pragma unroll
        for (int i = 0; i < 8; i++) {
            kcol[i] = f0[i]; kcol[8 + i] = f1[i]; kcol[16 + i] = f2[i]; kcol[24 + i] = f3[i];
        }
    }

    // ---- passes over d rows: scores -> softmax -> PV ----
    for (int pass = 0; pass < 3; pass++) {
        int d0 = pass * DCHUNK;
        int nrows = 65 - d0; if (nrows > DCHUNK) nrows = DCHUNK;
        // P1b scores
        if (colact) {
            for (int dl = 0; dl < nrows; dl++) {
                int d = d0 + dl;
                const uint4* q4 = reinterpret_cast<const uint4*>(&sQ[d * 32]);
                float sum = 0.f;
                #pragma unroll
                for (int p = 0; p < 4; p++) {
                    float qf[8]; unpack8(q4[p], qf);
                    #pragma unroll
                    for (int e = 0; e < 8; e++) sum += qf[e] * kcol[p * 8 + e];
                }
                u.S[dl * SPAD + t] = masked ? -1e9f : sum;
            }
        }
        __syncthreads();
        // P2 softmax (5 waves, row-strided)
        {
            int wid = t >> 6, lane = t & 63;
            for (int dl = wid; dl < nrows; dl += 5) {
                float* row = &u.S[dl * SPAD];
                float mx = -1e30f;
                for (int s = lane; s < SPAD; s += 64) mx = fmaxf(mx, row[s]);
                #pragma unroll
                for (int o = 32; o > 0; o >>= 1) mx = fmaxf(mx, __shfl_xor(mx, o, 64));
                float sum = 0.f;
                for (int s = lane; s < SPAD; s += 64) { float e_ = __expf(row[s] - mx); row[s] = e_; sum += e_; }
                #pragma unroll
                for (int o = 32; o > 0; o >>= 1) sum += __shfl_xor(sum, o, 64);
                float inv = 1.0f / sum;
                for (int s = lane; s < SPAD; s += 64) row[s] *= inv;
            }
        }
        __syncthreads();
        // P3 PV: thread = (eg 0..7)x(dl 0..39), active dl<nrows
        {
            int eg = t & 7, dl = t >> 3;
            if (dl < nrows) {
                int d = d0 + dl;
                float o0 = 0, o1 = 0, o2 = 0, o3 = 0;
                const float* prow = &u.S[dl * SPAD];
                for (int s = 0; s < SPAD; s++) {
                    float p = prow[s];
                    uint2 vv = *reinterpret_cast<const uint2*>(&sV[s * 32 + eg * 4]);
                    float v0, v1, v2, v3;
                    bfp2(vv.x, v0, v1); bfp2(vv.y, v2, v3);
                    o0 += p * v0; o1 += p * v1; o2 += p * v2; o3 += p * v3;
                }
                size_t obase = (((size_t)b * HID + g * 32 + eg * 4) * TQ + q) * TD + d;
                att[obase]                       = o0;
                att[obase + (size_t)TQ * TD]     = o1;
                att[obase + 2 * (size_t)TQ * TD] = o2;
                att[obase + 3 * (size_t)TQ * TD] = o3;
            }
        }
        __syncthreads();
    }
}

// ---------------- z = relu(gn2(agg)) + relu(gn_sc(scr)), in place on agg ----------------
__global__ void z_kernel(float* __restrict__ out, const float* __restrict__ scr,
                         const float* __restrict__ st2, const float* __restrict__ stsc,
                         const float* __restrict__ g2w, const float* __restrict__ g2b,
                         const float* __restrict__ gsw, const float* __restrict__ gsb)
{
    const float invcnt = 1.0f / (128.0f * NPIX);
    size_t total4 = (size_t)NB * COUT * (NPIX / 4);
    float4* o4 = reinterpret_cast<float4*>(out);
    const float4* s4 = reinterpret_cast<const float4*>(scr);
    for (size_t i = (size_t)blockIdx.x * blockDim.x + threadIdx.x; i < total4;
         i += (size_t)gridDim.x * blockDim.x) {
        size_t flat = i * 4;
        int c = (int)((flat / NPIX) % COUT);
        int b = (int)(flat / ((size_t)COUT * NPIX));
        int bg = b * 4 + (c >> 7);
        float2 p2 = gn_params(st2,  bg, invcnt);
        float2 ps = gn_params(stsc, bg, invcnt);
        float w2 = g2w[c] * p2.y, b2 = g2b[c] - p2.x * p2.y * g2w[c];
        float wsc = gsw[c] * ps.y, bsc = gsb[c] - ps.x * ps.y * gsw[c];
        float4 a = o4[i], r = s4[i], z;
        z.x = fmaxf(a.x * w2 + b2, 0.f) + fmaxf(r.x * wsc + bsc, 0.f);
        z.y = fmaxf(a.y * w2 + b2, 0.f) + fmaxf(r.y * wsc + bsc, 0.f);
        z.z = fmaxf(a.z * w2 + b2, 0.f) + fmaxf(r.z * wsc + bsc, 0.f);
        z.w = fmaxf(a.w * w2 + b2, 0.f) + fmaxf(r.w * wsc + bsc, 0.f);
        o4[i] = z;
    }
}

// ---------------- final gn_out, in place ----------------
__global__ void norm_kernel(float* __restrict__ out, const float* __restrict__ st3,
                            const float* __restrict__ gw, const float* __restrict__ gb)
{
    const float invcnt = 1.0f / (128.0f * NPIX);
    size_t total4 = (size_t)NB * COUT * (NPIX / 4);
    float4* o4 = reinterpret_cast<float4*>(out);
    for (size_t i = (size_t)blockIdx.x * blockDim.x + threadIdx.x; i < total4;
         i += (size_t)gridDim.x * blockDim.x) {
        size_t flat = i * 4;
        int c = (int)((flat / NPIX) % COUT);
        int b = (int)(flat / ((size_t)COUT * NPIX));
        int bg = b * 4 + (c >> 7);
        float2 p = gn_params(st3, bg, invcnt);
        float w_ = gw[c] * p.y, b_ = gb[c] - p.x * p.y * gw[c];
        float4 a = o4[i], z;
        z.x = a.x * w_ + b_; z.y = a.y * w_ + b_; z.z = a.z * w_ + b_; z.w = a.w * w_ + b_;
        o4[i] = z;
    }
}

extern "C" void kernel_launch(void* const* d_in, const int* in_sizes, int n_in,
                              void* d_out, int out_size, void* d_ws, size_t ws_size,
                              hipStream_t stream) {
    (void)in_sizes; (void)n_in; (void)out_size; (void)ws_size;
    const float* corr     = (const float*)d_in[0];
    const int*   smask    = (const int*)  d_in[1];
    const float* W_sc     = (const float*)d_in[2];
    const float* gn_sc_w  = (const float*)d_in[3];
    const float* gn_sc_b  = (const float*)d_in[4];
    const float* W_qkv    = (const float*)d_in[5];
    const float* b_qkv    = (const float*)d_in[6];
    const float* gn1_w    = (const float*)d_in[7];
    const float* gn1_b    = (const float*)d_in[8];
    const float* W_agg    = (const float*)d_in[9];
    const float* gn2_w    = (const float*)d_in[10];
    const float* gn2_b    = (const float*)d_in[11];
    const float* gn_out_w = (const float*)d_in[12];
    const float* gn_out_b = (const float*)d_in[13];
    float* out = (float*)d_out;

    float* ws    = (float*)d_ws;
    float* corrp = ws;                      // (B,128,TQ,TD)   8,519,680
    float* qp    = corrp + (size_t)8519680; // (B,256,TQ,TD)  17,039,360
    float* scr   = qp    + (size_t)17039360;// (B,512,TQ,TD)  34,078,720
    float* att   = scr   + (size_t)34078720;// (B,256,TQ,TD)  17,039,360
    float* m16   = att   + (size_t)17039360;// (B,256)         1,024
    float* stats = m16   + (size_t)1024;    // 4 x 32
    float* st_sc = stats, *st1 = stats + 32, *st2 = stats + 64, *st3 = stats + 96;

    hipMemsetAsync(stats, 0, 128 * sizeof(float), stream);
    mask_kernel<<<dim3(NB), dim3(256), 0, stream>>>(smask, m16);
    pool_kernel<<<dim3(2048), dim3(256), 0, stream>>>(corr, corrp);
    // residual conv: scr = W_sc x corrp
    gemm_kernel<0><<<dim3(260, 8, NB), dim3(256), 0, stream>>>(
        W_sc, corrp, scr, 512, 128, nullptr, nullptr, nullptr, nullptr, 0, 0.f);
    // q projection (pooled): qp = Wq x corrp + bq
    gemm_kernel<1><<<dim3(260, 4, NB), dim3(256), 0, stream>>>(
        W_qkv, corrp, qp, 256, 128, b_qkv, nullptr, nullptr, nullptr, 0, 0.f);
    stats_kernel<<<dim3(64, 16), dim3(256), 0, stream>>>(scr, st_sc, 128);
    attn_kernel<<<dim3(8, TQ, NB), dim3(320), 0, stream>>>(corr, W_qkv, b_qkv, qp, m16, att);
    stats_kernel<<<dim3(64, 16), dim3(256), 0, stream>>>(att, st1, 64);
    // agg conv with fused gn1+relu on input: out = W_agg x relu(gn1(att))
    gemm_kernel<2><<<dim3(260, 8, NB), dim3(256), 0, stream>>>(
        W_agg, att, out, 512, 256, nullptr, st1, gn1_w, gn1_b, 64, 1.0f / (64.0f * (float)NPIX));
    stats_kernel<<<dim3(64, 16), dim3(256), 0, stream>>>(out, st2, 128);
    z_kernel<<<dim3(4096), dim3(256), 0, stream>>>(out, scr, st2, st_sc, gn2_w, gn2_b, gn_sc_w, gn_sc_b);
    stats_kernel<<<dim3(64, 16), dim3(256), 0, stream>>>(out, st3, 128);
    norm_kernel<<<dim3(4096), dim3(256), 0, stream>>>(out, st3, gn_out_w, gn_out_b);
}

// Round 2
// 1811.902 us; speedup vs baseline: 2.8038x; 2.8038x over previous
//
#include <hip/hip_runtime.h>
#include <stdint.h>

#define NB    4
#define CIN   128
#define TQ    256
#define TS    257
#define TD    65
#define NPIX  (TQ*TD)     /* 16640 */
#define NKV   (TQ*TS)     /* 65792 */
#define COUT  512
#define HID   256
#define VROW  264         /* V global row pad (mult of 8) */
#define SROW  288         /* P/V LDS row length (9 k-steps of 32) */

typedef __attribute__((ext_vector_type(8))) short bf16x8;
typedef __attribute__((ext_vector_type(4))) float f32x4;

// ---------------- bf16 helpers ----------------
__device__ __forceinline__ unsigned short f2bf(float x) {
    union { float f; unsigned int i; } v; v.f = x;
    unsigned int r = v.i + 0x7fffu + ((v.i >> 16) & 1u);
    return (unsigned short)(r >> 16);
}

// ---------------- mask: exact gather (linspace step = 17, frac = 0) ----------------
__global__ void mask_kernel(const int* __restrict__ sm, float* __restrict__ m16) {
    int b = blockIdx.x; int t = threadIdx.x;           // 256 threads
    int i = t >> 4, j = t & 15;
    int v = sm[(size_t)b * 65536 + i * 17 * 256 + j * 17];
    m16[b * 256 + t] = (v != 0) ? 1.0f : 0.0f;
}

// ---------------- cst_pool on corr ----------------
__global__ void pool_kernel(const float* __restrict__ corr, float* __restrict__ corrp) {
    size_t total = (size_t)NB * CIN * TQ * TD;
    for (size_t idx = (size_t)blockIdx.x * blockDim.x + threadIdx.x; idx < total;
         idx += (size_t)gridDim.x * blockDim.x) {
        int d = (int)(idx % TD);
        size_t rest = idx / TD;                        // (b*C + c)*TQ + q
        const float* src = corr + rest * TS;
        float val;
        if (d == 0) val = src[0];
        else {
            int dd = d - 1; int i = dd >> 3, j = dd & 7;
            int s = 1 + i * 32 + j * 2;
            val = 0.25f * (src[s] + src[s + 1] + src[s + 16] + src[s + 17]);
        }
        corrp[idx] = val;
    }
}

// ---------------- group-norm stats (sum, sumsq) per contiguous (b,g) span ----------------
__global__ void stats_kernel(const float* __restrict__ x, float* __restrict__ st, int Cg) {
    size_t len = (size_t)Cg * NPIX;
    size_t base = (size_t)blockIdx.y * len;
    const float4* x4 = reinterpret_cast<const float4*>(x + base);
    size_t len4 = len >> 2;
    float s = 0.f, ss = 0.f;
    for (size_t i = (size_t)blockIdx.x * blockDim.x + threadIdx.x; i < len4;
         i += (size_t)gridDim.x * blockDim.x) {
        float4 v = x4[i];
        s  += v.x + v.y + v.z + v.w;
        ss += v.x * v.x + v.y * v.y + v.z * v.z + v.w * v.w;
    }
    #pragma unroll
    for (int o = 32; o > 0; o >>= 1) { s += __shfl_down(s, o, 64); ss += __shfl_down(ss, o, 64); }
    __shared__ float red[4][2];
    int wid = threadIdx.x >> 6, lane = threadIdx.x & 63;
    if (lane == 0) { red[wid][0] = s; red[wid][1] = ss; }
    __syncthreads();
    if (threadIdx.x == 0) {
        float S  = red[0][0] + red[1][0] + red[2][0] + red[3][0];
        float SS = red[0][1] + red[1][1] + red[2][1] + red[3][1];
        atomicAdd(&st[blockIdx.y * 2],     S);
        atomicAdd(&st[blockIdx.y * 2 + 1], SS);
    }
}

__device__ __forceinline__ float2 gn_params(const float* st, int bg, float invcnt) {
    float mu  = st[bg * 2] * invcnt;
    float var = st[bg * 2 + 1] * invcnt - mu * mu;
    float2 r; r.x = mu; r.y = rsqrtf(var + 1e-5f); return r;
}

// ---------------- tiled fp32 GEMM: Y(b,m,n) = sum_k W(m,k) X(b,k,n) ----------------
// MODE 0: plain  MODE 1: +bias[m]  MODE 2: gn+relu on X  MODE 3: +bias[m], write bf16 K/V
template<int MODE>
__global__ __launch_bounds__(256) void gemm_kernel(
    const float* __restrict__ W, const float* __restrict__ X, float* __restrict__ Y,
    int M, int K, int N,
    const float* __restrict__ bias,
    const float* __restrict__ stats, const float* __restrict__ gw, const float* __restrict__ gb,
    int Cg, float invcnt,
    unsigned short* __restrict__ kb, unsigned short* __restrict__ vb)
{
    int b  = blockIdx.z;
    int m0 = blockIdx.y * 64;
    int n0 = blockIdx.x * 64;
    __shared__ float sA[16][68];   // [k][m]
    __shared__ float sB[16][68];   // [k][n]
    int t = threadIdx.x;
    int tr = t >> 4, tc = t & 15;
    float acc[4][4] = {};
    const float* Xb = X + (size_t)b * K * N;
    for (int k0 = 0; k0 < K; k0 += 16) {
        {   // W tile 64m x 16k
            int r = t >> 4, c = t & 15;
            #pragma unroll
            for (int i = 0; i < 4; i++) {
                int m = m0 + r + i * 16;
                sA[c][r + i * 16] = W[(size_t)m * K + k0 + c];
            }
        }
        {   // X tile 16k x 64n (+transform)
            int r = t >> 6, c = t & 63;
            #pragma unroll
            for (int i = 0; i < 4; i++) {
                int k = k0 + r + i * 4;
                float v = Xb[(size_t)k * N + n0 + c];
                if (MODE == 2) {
                    int g = k / Cg;
                    float2 p = gn_params(stats, b * 4 + g, invcnt);
                    v = (v - p.x) * p.y * gw[k] + gb[k];
                    v = fmaxf(v, 0.0f);
                }
                sB[r + i * 4][c] = v;
            }
        }
        __syncthreads();
        #pragma unroll
        for (int kk = 0; kk < 16; kk++) {
            float4 a4 = *reinterpret_cast<const float4*>(&sA[kk][tr * 4]);
            float4 b4 = *reinterpret_cast<const float4*>(&sB[kk][tc * 4]);
            float av[4] = {a4.x, a4.y, a4.z, a4.w};
            float bv[4] = {b4.x, b4.y, b4.z, b4.w};
            #pragma unroll
            for (int i = 0; i < 4; i++)
                #pragma unroll
                for (int j = 0; j < 4; j++)
                    acc[i][j] += av[i] * bv[j];
        }
        __syncthreads();
    }
    if (MODE == 3) {
        // K channels (m<256): kb[(((b*8+g)*256+q)*257 + s)*32 + e]
        // V channels (m>=256): vb[(((b*8+g)*256+q)*32 + e)*264 + s]
        #pragma unroll
        for (int i = 0; i < 4; i++) {
            int m = m0 + tr * 4 + i;
            float bs = bias[m];
            #pragma unroll
            for (int j = 0; j < 4; j++) {
                int n = n0 + tc * 4 + j;
                unsigned q_ = (unsigned)n / 257u;
                unsigned s_ = (unsigned)n - q_ * 257u;
                unsigned short h = f2bf(acc[i][j] + bs);
                if (m < 256) {
                    int g = m >> 5, e = m & 31;
                    kb[((((size_t)b * 8 + g) * 256 + q_) * 257 + s_) * 32 + e] = h;
                } else {
                    int mm = m - 256; int g = mm >> 5, e = mm & 31;
                    vb[((((size_t)b * 8 + g) * 256 + q_) * 32 + e) * VROW + s_] = h;
                }
            }
        }
        return;
    }
    #pragma unroll
    for (int i = 0; i < 4; i++) {
        int m = m0 + tr * 4 + i;
        float bs = (MODE == 1) ? bias[m] : 0.0f;
        float4 r;
        r.x = acc[i][0] + bs; r.y = acc[i][1] + bs; r.z = acc[i][2] + bs; r.w = acc[i][3] + bs;
        *reinterpret_cast<float4*>(&Y[((size_t)b * M + m) * N + n0 + tc * 4]) = r;
    }
}

// ---------------- MFMA attention: QK^T + mask + softmax + PV ----------------
// grid (8, 256, 4) = (g, q, b); 320 threads = 5 waves, wave w owns d rows [16w, 16w+16)
__global__ __launch_bounds__(320) void attn_kernel(
    const unsigned short* __restrict__ kb,   // (B,8,TQ,257,32)  [s][e] e-contig
    const unsigned short* __restrict__ vb,   // (B,8,TQ,32,264)  [e][s] s-contig
    const float* __restrict__ qp,            // (B,256,TQ,TD) fp32
    const float* __restrict__ m16,           // (B,256)
    float* __restrict__ att)                 // (B,256,TQ,TD) fp32
{
    int g = blockIdx.x, q = blockIdx.y, b = blockIdx.z;
    int t = threadIdx.x;
    int w = t >> 6, lane = t & 63;
    int lm = lane & 15, lg = lane >> 4;

    // sPK: phase1 = sK[272][32] (8704 shorts); phase2 = P tiles, wave w at [w*4608 .. +4608)
    __shared__ __align__(16) unsigned short sPK[23040];
    __shared__ __align__(16) unsigned short sV[32 * SROW];   // [e][s], s padded to 288

    size_t tile = ((size_t)(b * 8 + g) * 256 + q);
    // ---- stage K: 257*32 shorts = 1028 uint4, contiguous ----
    {
        const uint4* ksrc = reinterpret_cast<const uint4*>(kb + tile * (257 * 32));
        uint4* kdst = reinterpret_cast<uint4*>(sPK);
        for (int i = t; i < 1028; i += 320) kdst[i] = ksrc[i];
        uint4 z; z.x = z.y = z.z = z.w = 0;
        for (int i = t; i < 60; i += 320) kdst[1028 + i] = z;   // rows 257..271 = 0
    }
    // ---- stage V: rows of 264 shorts -> LDS rows of 288 ----
    {
        const uint4* vsrc = reinterpret_cast<const uint4*>(vb + tile * (32 * VROW));
        for (int i = t; i < 1056; i += 320) {
            int e = i / 33, sj = i % 33;
            *reinterpret_cast<uint4*>(&sV[e * SROW + sj * 8]) = vsrc[i];
        }
        for (int i = t; i < 32 * 31; i += 320) {            // zero s = 257..287
            int e = i / 31, s = 257 + i % 31;
            sV[e * SROW + s] = 0;
        }
    }
    // ---- Q A-frag from global (per-wave d-tile), rows d>=65 -> 0 ----
    bf16x8 qa;
    {
        int d = w * 16 + lm;
        const float* qb2 = qp + ((size_t)(b * HID + g * 32) * TQ + q) * TD + d;
        #pragma unroll
        for (int j = 0; j < 8; j++) {
            int e = lg * 8 + j;
            float v = (d < TD) ? qb2[(size_t)e * TQ * TD] : 0.0f;
            qa[j] = (short)f2bf(v);
        }
    }
    __syncthreads();

    // ---- scores: 17 s-tiles of 16 ----
    f32x4 c[17];
    f32x4 zero4 = {0.f, 0.f, 0.f, 0.f};
    #pragma unroll
    for (int tt = 0; tt < 17; tt++) {
        const bf16x8* kf = reinterpret_cast<const bf16x8*>(&sPK[(tt * 16 + lm) * 32 + lg * 8]);
        c[tt] = __builtin_amdgcn_mfma_f32_16x16x32_bf16(qa, *kf, zero4, 0, 0, 0);
    }
    __syncthreads();   // everyone done reading sK before P overwrites it

    // ---- mask + softmax (col s = tt*16 + lm; rows are regs) ----
    #pragma unroll
    for (int tt = 0; tt < 17; tt++) {
        int s = tt * 16 + lm;
        float mval = (s >= 1 && s < TS) ? m16[b * 256 + s - 1] : 0.0f;
        bool act = (s == 0) || (s < TS && mval != 0.0f);
        if (!act) { c[tt][0] = -1e9f; c[tt][1] = -1e9f; c[tt][2] = -1e9f; c[tt][3] = -1e9f; }
    }
    float inv[4];
    #pragma unroll
    for (int r = 0; r < 4; r++) {
        float mx = c[0][r];
        #pragma unroll
        for (int tt = 1; tt < 17; tt++) mx = fmaxf(mx, c[tt][r]);
        mx = fmaxf(mx, __shfl_xor(mx, 1)); mx = fmaxf(mx, __shfl_xor(mx, 2));
        mx = fmaxf(mx, __shfl_xor(mx, 4)); mx = fmaxf(mx, __shfl_xor(mx, 8));
        float sm = 0.f;
        #pragma unroll
        for (int tt = 0; tt < 17; tt++) { float e_ = __expf(c[tt][r] - mx); c[tt][r] = e_; sm += e_; }
        sm += __shfl_xor(sm, 1); sm += __shfl_xor(sm, 2);
        sm += __shfl_xor(sm, 4); sm += __shfl_xor(sm, 8);
        inv[r] = 1.0f / sm;
    }
    // ---- write P (bf16) to wave-private LDS region, A-layout [d_local][s] ----
    unsigned short* sPw = sPK + w * (16 * SROW);
    #pragma unroll
    for (int tt = 0; tt < 17; tt++) {
        #pragma unroll
        for (int r = 0; r < 4; r++) {
            sPw[(lg * 4 + r) * SROW + tt * 16 + lm] = f2bf(c[tt][r] * inv[r]);
        }
    }
    if (lane < 16) {   // zero pad cols 272..287
        uint4 z; z.x = z.y = z.z = z.w = 0;
        *reinterpret_cast<uint4*>(&sPw[lane * SROW + 272]) = z;
        *reinterpret_cast<uint4*>(&sPw[lane * SROW + 280]) = z;
    }
    __syncthreads();

    // ---- PV: out[d][e], 2 e-tiles, 9 k-steps of 32 ----
    f32x4 o0 = zero4, o1 = zero4;
    #pragma unroll
    for (int kk = 0; kk < 9; kk++) {
        const bf16x8 pa = *reinterpret_cast<const bf16x8*>(&sPw[lm * SROW + kk * 32 + lg * 8]);
        const bf16x8 v0 = *reinterpret_cast<const bf16x8*>(&sV[(lm) * SROW + kk * 32 + lg * 8]);
        const bf16x8 v1 = *reinterpret_cast<const bf16x8*>(&sV[(16 + lm) * SROW + kk * 32 + lg * 8]);
        o0 = __builtin_amdgcn_mfma_f32_16x16x32_bf16(pa, v0, o0, 0, 0, 0);
        o1 = __builtin_amdgcn_mfma_f32_16x16x32_bf16(pa, v1, o1, 0, 0, 0);
    }
    // ---- store: C layout row d = 16w + lg*4 + r, col e = nt*16 + lm ----
    #pragma unroll
    for (int r = 0; r < 4; r++) {
        int d = w * 16 + lg * 4 + r;
        if (d < TD) {
            size_t base = ((size_t)(b * HID + g * 32) * TQ + q) * TD + d;
            att[base + (size_t)(lm) * TQ * TD]      = o0[r];
            att[base + (size_t)(16 + lm) * TQ * TD] = o1[r];
        }
    }
}

// ---------------- z = relu(gn2(agg)) + relu(gn_sc(scr)), in place on agg ----------------
__global__ void z_kernel(float* __restrict__ out, const float* __restrict__ scr,
                         const float* __restrict__ st2, const float* __restrict__ stsc,
                         const float* __restrict__ g2w, const float* __restrict__ g2b,
                         const float* __restrict__ gsw, const float* __restrict__ gsb)
{
    const float invcnt = 1.0f / (128.0f * NPIX);
    size_t total4 = (size_t)NB * COUT * (NPIX / 4);
    float4* o4 = reinterpret_cast<float4*>(out);
    const float4* s4 = reinterpret_cast<const float4*>(scr);
    for (size_t i = (size_t)blockIdx.x * blockDim.x + threadIdx.x; i < total4;
         i += (size_t)gridDim.x * blockDim.x) {
        size_t flat = i * 4;
        int c = (int)((flat / NPIX) % COUT);
        int b = (int)(flat / ((size_t)COUT * NPIX));
        int bg = b * 4 + (c >> 7);
        float2 p2 = gn_params(st2,  bg, invcnt);
        float2 ps = gn_params(stsc, bg, invcnt);
        float w2 = g2w[c] * p2.y, b2 = g2b[c] - p2.x * p2.y * g2w[c];
        float wsc = gsw[c] * ps.y, bsc = gsb[c] - ps.x * ps.y * gsw[c];
        float4 a = o4[i], r = s4[i], z;
        z.x = fmaxf(a.x * w2 + b2, 0.f) + fmaxf(r.x * wsc + bsc, 0.f);
        z.y = fmaxf(a.y * w2 + b2, 0.f) + fmaxf(r.y * wsc + bsc, 0.f);
        z.z = fmaxf(a.z * w2 + b2, 0.f) + fmaxf(r.z * wsc + bsc, 0.f);
        z.w = fmaxf(a.w * w2 + b2, 0.f) + fmaxf(r.w * wsc + bsc, 0.f);
        o4[i] = z;
    }
}

// ---------------- final gn_out, in place ----------------
__global__ void norm_kernel(float* __restrict__ out, const float* __restrict__ st3,
                            const float* __restrict__ gw, const float* __restrict__ gb)
{
    const float invcnt = 1.0f / (128.0f * NPIX);
    size_t total4 = (size_t)NB * COUT * (NPIX / 4);
    float4* o4 = reinterpret_cast<float4*>(out);
    for (size_t i = (size_t)blockIdx.x * blockDim.x + threadIdx.x; i < total4;
         i += (size_t)gridDim.x * blockDim.x) {
        size_t flat = i * 4;
        int c = (int)((flat / NPIX) % COUT);
        int b = (int)(flat / ((size_t)COUT * NPIX));
        int bg = b * 4 + (c >> 7);
        float2 p = gn_params(st3, bg, invcnt);
        float w_ = gw[c] * p.y, b_ = gb[c] - p.x * p.y * gw[c];
        float4 a = o4[i], z;
        z.x = a.x * w_ + b_; z.y = a.y * w_ + b_; z.z = a.z * w_ + b_; z.w = a.w * w_ + b_;
        o4[i] = z;
    }
}

extern "C" void kernel_launch(void* const* d_in, const int* in_sizes, int n_in,
                              void* d_out, int out_size, void* d_ws, size_t ws_size,
                              hipStream_t stream) {
    (void)in_sizes; (void)n_in; (void)out_size; (void)ws_size;
    const float* corr     = (const float*)d_in[0];
    const int*   smask    = (const int*)  d_in[1];
    const float* W_sc     = (const float*)d_in[2];
    const float* gn_sc_w  = (const float*)d_in[3];
    const float* gn_sc_b  = (const float*)d_in[4];
    const float* W_qkv    = (const float*)d_in[5];
    const float* b_qkv    = (const float*)d_in[6];
    const float* gn1_w    = (const float*)d_in[7];
    const float* gn1_b    = (const float*)d_in[8];
    const float* W_agg    = (const float*)d_in[9];
    const float* gn2_w    = (const float*)d_in[10];
    const float* gn2_b    = (const float*)d_in[11];
    const float* gn_out_w = (const float*)d_in[12];
    const float* gn_out_b = (const float*)d_in[13];
    float* out = (float*)d_out;

    float* ws    = (float*)d_ws;
    float* corrp = ws;                        //  8,519,680 f
    float* qp    = corrp + (size_t)8519680;   // 17,039,360 f
    float* att   = qp    + (size_t)17039360;  // 17,039,360 f
    unsigned short* kbuf = (unsigned short*)(att + (size_t)17039360); // 67,371,008 us
    unsigned short* vbuf = kbuf + (size_t)67371008;                   // 69,206,016 us
    float* m16   = (float*)(vbuf + (size_t)69206016);                 // 1,024 f
    float* stats = m16 + 1024;                                        // 128 f
    float* scr   = (float*)kbuf;              // aliases K/V (dead after attn), 34,078,720 f
    float* st_sc = stats, *st1 = stats + 32, *st2 = stats + 64, *st3 = stats + 96;

    hipMemsetAsync(stats, 0, 128 * sizeof(float), stream);
    mask_kernel<<<dim3(NB), dim3(256), 0, stream>>>(smask, m16);
    pool_kernel<<<dim3(2048), dim3(256), 0, stream>>>(corr, corrp);
    // q projection (pooled): qp = Wq x corrp + bq
    gemm_kernel<1><<<dim3(260, 4, NB), dim3(256), 0, stream>>>(
        W_qkv, corrp, qp, 256, 128, NPIX, b_qkv, nullptr, nullptr, nullptr, 0, 0.f, nullptr, nullptr);
    // K/V projection over full corr -> bf16 K/V buffers
    gemm_kernel<3><<<dim3(1028, 8, NB), dim3(256), 0, stream>>>(
        W_qkv + (size_t)256 * 128, corr, nullptr, 512, 128, NKV, b_qkv + 256,
        nullptr, nullptr, nullptr, 0, 0.f, kbuf, vbuf);
    attn_kernel<<<dim3(8, TQ, NB), dim3(320), 0, stream>>>(kbuf, vbuf, qp, m16, att);
    stats_kernel<<<dim3(64, 16), dim3(256), 0, stream>>>(att, st1, 64);
    // residual conv: scr = W_sc x corrp  (scr aliases dead K/V space)
    gemm_kernel<0><<<dim3(260, 8, NB), dim3(256), 0, stream>>>(
        W_sc, corrp, scr, 512, 128, NPIX, nullptr, nullptr, nullptr, nullptr, 0, 0.f, nullptr, nullptr);
    stats_kernel<<<dim3(64, 16), dim3(256), 0, stream>>>(scr, st_sc, 128);
    // agg conv with fused gn1+relu on input: out = W_agg x relu(gn1(att))
    gemm_kernel<2><<<dim3(260, 8, NB), dim3(256), 0, stream>>>(
        W_agg, att, out, 512, 256, NPIX, nullptr, st1, gn1_w, gn1_b, 64, 1.0f / (64.0f * (float)NPIX),
        nullptr, nullptr);
    stats_kernel<<<dim3(64, 16), dim3(256), 0, stream>>>(out, st2, 128);
    z_kernel<<<dim3(4096), dim3(256), 0, stream>>>(out, scr, st2, st_sc, gn2_w, gn2_b, gn_sc_w, gn_sc_b);
    stats_kernel<<<dim3(64, 16), dim3(256), 0, stream>>>(out, st3, 128);
    norm_kernel<<<dim3(4096), dim3(256), 0, stream>>>(out, st3, gn_out_w, gn_out_b);
}

// Round 3
// 1103.120 us; speedup vs baseline: 4.6053x; 1.6425x over previous
//
#include <hip/hip_runtime.h>
#include <stdint.h>

#define NB    4
#define TQ    256
#define TS    257
#define TD    65
#define NPIX  16640        /* TQ*TD */
#define NPADQ 264          /* padded s per q */
#define NPAD  67584        /* 256*264 */
#define COUT  512
#define HID   256

typedef __attribute__((ext_vector_type(8))) short bf16x8;
typedef __attribute__((ext_vector_type(4))) float f32x4;

// ---------------- bf16 helpers ----------------
__device__ __forceinline__ float bf2f(unsigned short u) {
    union { unsigned int i; float f; } v; v.i = ((unsigned int)u) << 16; return v.f;
}
__device__ __forceinline__ unsigned short f2bf(float x) {
    union { float f; unsigned int i; } v; v.f = x;
    unsigned int r = v.i + 0x7fffu + ((v.i >> 16) & 1u);
    return (unsigned short)(r >> 16);
}

__device__ __forceinline__ float2 gn_params(const float* st, int bg, float invcnt) {
    float mu  = st[bg * 2] * invcnt;
    float var = st[bg * 2 + 1] * invcnt - mu * mu;
    float2 r; r.x = mu; r.y = rsqrtf(var + 1e-5f); return r;
}

// ---------------- weight cast fp32 -> bf16 ----------------
__global__ void wprep_kernel(const float* __restrict__ wq, const float* __restrict__ wsc,
                             const float* __restrict__ wagg, unsigned short* __restrict__ wb) {
    int i = blockIdx.x * 256 + threadIdx.x;   // grid 1152 -> 294912
    float v;
    if (i < 98304) v = wq[i];
    else if (i < 163840) v = wsc[i - 98304];
    else v = wagg[i - 163840];
    wb[i] = f2bf(v);
}

// ---------------- mask: exact gather (linspace step = 17, frac = 0) ----------------
__global__ void mask_kernel(const int* __restrict__ sm, float* __restrict__ m16) {
    int b = blockIdx.x; int t = threadIdx.x;
    int i = t >> 4, j = t & 15;
    int v = sm[(size_t)b * 65536 + i * 17 * 256 + j * 17];
    m16[b * 256 + t] = (v != 0) ? 1.0f : 0.0f;
}

// ---------------- fused transpose + pool: corr -> corrT bf16 [n'][128], corrpT bf16 [n][128] ----
// grid (256 q, 2 chalf, 4 b), 256 threads
__global__ __launch_bounds__(256) void tpool_kernel(
    const float* __restrict__ corr,
    unsigned short* __restrict__ corrT,    // [b][NPAD][128]
    unsigned short* __restrict__ corrpT)   // [b][NPIX][128]
{
    int q = blockIdx.x, ch = blockIdx.y, b = blockIdx.z;
    int t = threadIdx.x;
    __shared__ unsigned short sT[264 * 66];

    // load 64 channels x 257 s, coalesced over s; write [s][c] bf16
    {
        int laneT = t & 63; int crow = t >> 6;
        for (int c = crow; c < 64; c += 4) {
            const float* src = corr + (((size_t)b * 128 + ch * 64 + c) * 256 + q) * 257;
            for (int s = laneT; s < 257; s += 64) sT[s * 66 + c] = f2bf(src[s]);
        }
    }
    // zero pad rows 257..263
    for (int idx = t; idx < 7 * 66; idx += 256) {
        int s = 257 + idx / 66, c = idx % 66;
        sT[s * 66 + c] = 0;
    }
    __syncthreads();

    // corrT out: 264 rows x 32 uints (this chalf)
    {
        unsigned int* dst = (unsigned int*)corrT;
        size_t base = (size_t)b * (NPAD * 64) + (size_t)q * (264 * 64) + ch * 32;
        for (int idx = t; idx < 264 * 32; idx += 256) {
            int s = idx >> 5, cu = idx & 31;
            unsigned int v = (unsigned int)sT[s * 66 + 2 * cu] |
                             ((unsigned int)sT[s * 66 + 2 * cu + 1] << 16);
            dst[base + (size_t)s * 64 + cu] = v;
        }
    }
    // pooled out: 65 d x 32 uints
    {
        unsigned int* dst = (unsigned int*)corrpT;
        size_t base = (size_t)b * (NPIX * 64) + (size_t)q * (65 * 64) + ch * 32;
        for (int idx = t; idx < 65 * 32; idx += 256) {
            int d = idx >> 5, cu = idx & 31;
            float x0, x1;
            if (d == 0) {
                x0 = bf2f(sT[0 * 66 + 2 * cu]); x1 = bf2f(sT[0 * 66 + 2 * cu + 1]);
            } else {
                int dd = d - 1; int i = dd >> 3, j = dd & 7;
                int s = 1 + i * 32 + j * 2;
                int c0 = 2 * cu, c1 = 2 * cu + 1;
                x0 = 0.25f * (bf2f(sT[s*66+c0]) + bf2f(sT[(s+1)*66+c0]) +
                              bf2f(sT[(s+16)*66+c0]) + bf2f(sT[(s+17)*66+c0]));
                x1 = 0.25f * (bf2f(sT[s*66+c1]) + bf2f(sT[(s+1)*66+c1]) +
                              bf2f(sT[(s+16)*66+c1]) + bf2f(sT[(s+17)*66+c1]));
            }
            unsigned int v = (unsigned int)f2bf(x0) | ((unsigned int)f2bf(x1) << 16);
            dst[base + (size_t)d * 64 + cu] = v;
        }
    }
}

// ---------------- unified MFMA GEMM ----------------
// X bf16 [b][Nn][KT] k-contig; Wb bf16 [M][KT].
// MODE 0 (Q):  out Y16[b][n][256] bf16, +bias, mfma(W,X) -> regs = 4 consecutive m
// MODE 1 (KV): m<256 -> kbuf [(b,g,q)][s][32e] scattered b16; m>=256 -> vbuf [b][mv][NPAD] uint2
// MODE 2 (SC): out Yf fp32 [b][512][NPIX]
// MODE 3 (AGG): like SC but gn1+relu transform on X during staging
template<int MODE, int KT>
__global__ __launch_bounds__(256) void mgemm_kernel(
    const unsigned short* __restrict__ X,
    const unsigned short* __restrict__ Wb,
    int Nn,
    float* __restrict__ Yf,
    unsigned short* __restrict__ Y16,
    unsigned short* __restrict__ kb,
    unsigned short* __restrict__ vb,
    const float* __restrict__ bias,
    const float* __restrict__ st, const float* __restrict__ gw, const float* __restrict__ gb,
    float invcnt)
{
    int b  = blockIdx.z;
    int n0 = blockIdx.x * 128;
    int m0 = blockIdx.y * 128;
    int t = threadIdx.x;
    int w = t >> 6, lane = t & 63;
    int lm = lane & 15, lg = lane >> 4;
    int wn = (w & 1) * 64, wm = (w >> 1) * 64;

    __shared__ __align__(16) unsigned short sX[16384];
    __shared__ __align__(16) unsigned short sW[16384];

    f32x4 acc[4][4];
    #pragma unroll
    for (int i = 0; i < 4; i++)
        #pragma unroll
        for (int j = 0; j < 4; j++) { acc[i][j][0]=0.f; acc[i][j][1]=0.f; acc[i][j][2]=0.f; acc[i][j][3]=0.f; }

    for (int kc = 0; kc < KT / 128; kc++) {
        // stage: 2048 uint4 each, direct copy (swizzled k-groups)
        for (int i = t; i < 2048; i += 256) {
            int r_ = i >> 4, kq = i & 15;
            uint4 xv = *(const uint4*)&X[((size_t)b * Nn + n0 + r_) * KT + kc * 128 + (kq << 3)];
            if (MODE == 3) {
                union { uint4 v; unsigned short us[8]; } u; u.v = xv;
                int c0 = kc * 128 + (kq << 3);
                float2 p = gn_params(st, b * 4 + (c0 >> 6), invcnt);
                #pragma unroll
                for (int jj = 0; jj < 8; jj++) {
                    int cc = c0 + jj;
                    float v = bf2f(u.us[jj]);
                    v = fmaxf((v - p.x) * p.y * gw[cc] + gb[cc], 0.0f);
                    u.us[jj] = f2bf(v);
                }
                xv = u.v;
            }
            *(uint4*)&sX[r_ * 128 + ((kq ^ (r_ & 15)) << 3)] = xv;
            uint4 wv = *(const uint4*)&Wb[((size_t)(m0 + r_)) * KT + kc * 128 + (kq << 3)];
            *(uint4*)&sW[r_ * 128 + ((kq ^ (r_ & 15)) << 3)] = wv;
        }
        __syncthreads();
        #pragma unroll
        for (int kk = 0; kk < 4; kk++) {
            int kg = (kk << 2) | lg;
            bf16x8 af[4], bw[4];
            #pragma unroll
            for (int ii = 0; ii < 4; ii++)
                af[ii] = *(const bf16x8*)&sX[(wn + ii * 16 + lm) * 128 + ((kg ^ lm) << 3)];
            #pragma unroll
            for (int jj = 0; jj < 4; jj++)
                bw[jj] = *(const bf16x8*)&sW[(wm + jj * 16 + lm) * 128 + ((kg ^ lm) << 3)];
            #pragma unroll
            for (int ii = 0; ii < 4; ii++)
                #pragma unroll
                for (int jj = 0; jj < 4; jj++) {
                    if (MODE == 0)
                        acc[ii][jj] = __builtin_amdgcn_mfma_f32_16x16x32_bf16(bw[jj], af[ii], acc[ii][jj], 0,0,0);
                    else
                        acc[ii][jj] = __builtin_amdgcn_mfma_f32_16x16x32_bf16(af[ii], bw[jj], acc[ii][jj], 0,0,0);
                }
        }
        __syncthreads();
    }

    if (MODE == 0) {
        // regs = 4 consecutive m (row = lg*4+r), col n = lm
        #pragma unroll
        for (int ii = 0; ii < 4; ii++) {
            int n = n0 + wn + ii * 16 + lm;
            #pragma unroll
            for (int jj = 0; jj < 4; jj++) {
                int mb = m0 + wm + jj * 16 + lg * 4;
                union { unsigned short us[4]; uint2 v; } pk;
                #pragma unroll
                for (int r = 0; r < 4; r++) pk.us[r] = f2bf(acc[ii][jj][r] + bias[mb + r]);
                *(uint2*)&Y16[((size_t)b * NPIX + n) * 256 + mb] = pk.v;
            }
        }
    } else if (MODE == 1) {
        if (m0 < 256) {   // K half: scattered b16 into [(b,g,q)][s][32]
            #pragma unroll
            for (int ii = 0; ii < 4; ii++) {
                #pragma unroll
                for (int r = 0; r < 4; r++) {
                    unsigned int np = (unsigned int)(n0 + wn + ii * 16 + lg * 4 + r);
                    unsigned int qq = np / 264u;
                    unsigned int s  = np - qq * 264u;
                    #pragma unroll
                    for (int jj = 0; jj < 4; jj++) {
                        int m = m0 + wm + jj * 16 + lm;
                        int gch = m >> 5, e = m & 31;
                        kb[(((size_t)(b * 8 + gch) * 256 + qq) * 264 + s) * 32 + e] =
                            f2bf(acc[ii][jj][r] + bias[m]);
                    }
                }
            }
        } else {          // V half: uint2 into [b][mv][NPAD]
            #pragma unroll
            for (int ii = 0; ii < 4; ii++) {
                int nb = n0 + wn + ii * 16 + lg * 4;
                #pragma unroll
                for (int jj = 0; jj < 4; jj++) {
                    int m = m0 + wm + jj * 16 + lm;
                    int mv = m - 256;
                    union { unsigned short us[4]; uint2 v; } pk;
                    #pragma unroll
                    for (int r = 0; r < 4; r++) pk.us[r] = f2bf(acc[ii][jj][r] + bias[m]);
                    *(uint2*)&vb[((size_t)b * 256 + mv) * NPAD + nb] = pk.v;
                }
            }
        }
    } else {
        // fp32 [b][512][NPIX], regs = 4 consecutive n
        #pragma unroll
        for (int ii = 0; ii < 4; ii++) {
            int nb = n0 + wn + ii * 16 + lg * 4;
            #pragma unroll
            for (int jj = 0; jj < 4; jj++) {
                int m = m0 + wm + jj * 16 + lm;
                *(f32x4*)&Yf[((size_t)b * COUT + m) * NPIX + nb] = acc[ii][jj];
            }
        }
    }
}

// ---------------- MFMA attention, zero barriers ----------------
// grid (8, 256, 4) = (g, q, b); 320 threads = 5 waves, wave w owns d in [16w,16w+16)
__global__ __launch_bounds__(320) void attn_kernel(
    const unsigned short* __restrict__ kb,   // [(b,g,q)][264 s][32 e]
    const unsigned short* __restrict__ vb,   // [b][256 ch][NPAD]
    const unsigned short* __restrict__ qpT,  // [b][NPIX][256]
    const float* __restrict__ m16,
    unsigned short* __restrict__ attT)       // [b][NPIX][256]
{
    int g = blockIdx.x, q = blockIdx.y, b = blockIdx.z;
    int t = threadIdx.x;
    int w = t >> 6, lane = t & 63;
    int lm = lane & 15, lg = lane >> 4;

    __shared__ __align__(16) unsigned short sP[23040];   // 5 waves x 16 x 288
    unsigned short* sPw = sP + w * 4608;

    // Q frag (clamped row, zero lanes d>=65)
    int d = w * 16 + lm;
    int dc = d < 64 ? d : 64;
    bf16x8 qa = *(const bf16x8*)&qpT[((size_t)b * NPIX + q * 65 + dc) * 256 + g * 32 + lg * 8];
    if (d >= TD) { bf16x8 z = {}; qa = z; }

    // scores: 17 s-tiles, K frags straight from global (L1-reused across waves)
    f32x4 zero4 = {0.f, 0.f, 0.f, 0.f};
    f32x4 c[17];
    size_t kb0 = ((size_t)(b * 8 + g) * 256 + q) * (264 * 32);
    #pragma unroll
    for (int tt = 0; tt < 17; tt++) {
        bf16x8 kf = *(const bf16x8*)&kb[kb0 + (size_t)(tt * 16 + lm) * 32 + lg * 8];
        c[tt] = __builtin_amdgcn_mfma_f32_16x16x32_bf16(qa, kf, zero4, 0, 0, 0);
    }
    // mask
    #pragma unroll
    for (int tt = 0; tt < 17; tt++) {
        int s = tt * 16 + lm;
        float mval = (s >= 1 && s < TS) ? m16[b * 256 + s - 1] : 0.0f;
        bool act = (s == 0) || (s < TS && mval != 0.0f);
        if (!act) { c[tt][0] = -1e9f; c[tt][1] = -1e9f; c[tt][2] = -1e9f; c[tt][3] = -1e9f; }
    }
    // softmax per register-row
    float inv[4];
    #pragma unroll
    for (int r = 0; r < 4; r++) {
        float mx = c[0][r];
        #pragma unroll
        for (int tt = 1; tt < 17; tt++) mx = fmaxf(mx, c[tt][r]);
        mx = fmaxf(mx, __shfl_xor(mx, 1)); mx = fmaxf(mx, __shfl_xor(mx, 2));
        mx = fmaxf(mx, __shfl_xor(mx, 4)); mx = fmaxf(mx, __shfl_xor(mx, 8));
        float sm = 0.f;
        #pragma unroll
        for (int tt = 0; tt < 17; tt++) { float e_ = __expf(c[tt][r] - mx); c[tt][r] = e_; sm += e_; }
        sm += __shfl_xor(sm, 1); sm += __shfl_xor(sm, 2);
        sm += __shfl_xor(sm, 4); sm += __shfl_xor(sm, 8);
        inv[r] = 1.0f / sm;
    }
    // P -> wave-private swizzled LDS (A-layout [d][s])
    #pragma unroll
    for (int tt = 0; tt < 17; tt++) {
        int s = tt * 16 + lm;
        int sg = s >> 3, sl = s & 7;
        #pragma unroll
        for (int r = 0; r < 4; r++) {
            int dd = lg * 4 + r;
            sPw[dd * 288 + ((sg ^ (dd & 3)) << 3) + sl] = f2bf(c[tt][r] * inv[r]);
        }
    }
    // zero s in [272,288)
    for (int idx = lane; idx < 256; idx += 64) {
        int dd = idx >> 4, s = 272 + (idx & 15);
        int sg = s >> 3;
        sPw[dd * 288 + ((sg ^ (dd & 3)) << 3) + (s & 7)] = 0;
    }
    // PV: V frags straight from global; P from wave-private LDS (no barrier needed)
    f32x4 o0 = zero4, o1 = zero4;
    size_t vb0 = ((size_t)b * 256 + g * 32) * NPAD + (size_t)q * 264;
    #pragma unroll
    for (int kk = 0; kk < 9; kk++) {
        int kg = kk * 4 + lg;
        bf16x8 pa = *(const bf16x8*)&sPw[lm * 288 + ((kg ^ (lm & 3)) << 3)];
        bf16x8 v0 = *(const bf16x8*)&vb[vb0 + (size_t)lm * NPAD + kk * 32 + lg * 8];
        bf16x8 v1 = *(const bf16x8*)&vb[vb0 + (size_t)(16 + lm) * NPAD + kk * 32 + lg * 8];
        o0 = __builtin_amdgcn_mfma_f32_16x16x32_bf16(pa, v0, o0, 0, 0, 0);
        o1 = __builtin_amdgcn_mfma_f32_16x16x32_bf16(pa, v1, o1, 0, 0, 0);
    }
    // store attT bf16 [n][256]
    #pragma unroll
    for (int r = 0; r < 4; r++) {
        int dd = w * 16 + lg * 4 + r;
        if (dd < TD) {
            size_t nn = (size_t)b * NPIX + q * 65 + dd;
            attT[nn * 256 + g * 32 + lm]      = f2bf(o0[r]);
            attT[nn * 256 + g * 32 + 16 + lm] = f2bf(o1[r]);
        }
    }
}

// ---------------- stats over bf16 attT [b][NPIX][256], groups of 64 channels ----------------
__global__ void stats1_kernel(const unsigned short* __restrict__ attT, float* __restrict__ st) {
    int b = blockIdx.y;
    int t = threadIdx.x;
    int e8 = t & 31, g = e8 >> 3;
    int lane = t & 63;
    float s = 0.f, ss = 0.f;
    for (int r = blockIdx.x * 8 + (t >> 5); r < NPIX; r += gridDim.x * 8) {
        union { uint4 v; unsigned short us[8]; } u;
        u.v = *(const uint4*)&attT[((size_t)b * NPIX + r) * 256 + e8 * 8];
        #pragma unroll
        for (int j = 0; j < 8; j++) { float x = bf2f(u.us[j]); s += x; ss += x * x; }
    }
    s += __shfl_down(s, 32); ss += __shfl_down(ss, 32);
    s += __shfl_down(s, 4);  ss += __shfl_down(ss, 4);
    s += __shfl_down(s, 2);  ss += __shfl_down(ss, 2);
    s += __shfl_down(s, 1);  ss += __shfl_down(ss, 1);
    if (lane < 32 && (lane & 7) == 0) {
        atomicAdd(&st[(b * 4 + g) * 2],     s);
        atomicAdd(&st[(b * 4 + g) * 2 + 1], ss);
    }
}

// ---------------- stats over fp32 [b][C][NPIX], contiguous (b,g) spans ----------------
__global__ void stats_kernel(const float* __restrict__ x, float* __restrict__ st, int Cg) {
    size_t len = (size_t)Cg * NPIX;
    size_t base = (size_t)blockIdx.y * len;
    const float4* x4 = reinterpret_cast<const float4*>(x + base);
    size_t len4 = len >> 2;
    float s = 0.f, ss = 0.f;
    for (size_t i = (size_t)blockIdx.x * blockDim.x + threadIdx.x; i < len4;
         i += (size_t)gridDim.x * blockDim.x) {
        float4 v = x4[i];
        s  += v.x + v.y + v.z + v.w;
        ss += v.x * v.x + v.y * v.y + v.z * v.z + v.w * v.w;
    }
    #pragma unroll
    for (int o = 32; o > 0; o >>= 1) { s += __shfl_down(s, o, 64); ss += __shfl_down(ss, o, 64); }
    __shared__ float red[4][2];
    int wid = threadIdx.x >> 6, lane = threadIdx.x & 63;
    if (lane == 0) { red[wid][0] = s; red[wid][1] = ss; }
    __syncthreads();
    if (threadIdx.x == 0) {
        float S  = red[0][0] + red[1][0] + red[2][0] + red[3][0];
        float SS = red[0][1] + red[1][1] + red[2][1] + red[3][1];
        atomicAdd(&st[blockIdx.y * 2],     S);
        atomicAdd(&st[blockIdx.y * 2 + 1], SS);
    }
}

// ---------------- z = relu(gn2(agg)) + relu(gn_sc(scr)), in place on agg ----------------
__global__ void z_kernel(float* __restrict__ out, const float* __restrict__ scr,
                         const float* __restrict__ st2, const float* __restrict__ stsc,
                         const float* __restrict__ g2w, const float* __restrict__ g2b,
                         const float* __restrict__ gsw, const float* __restrict__ gsb)
{
    const float invcnt = 1.0f / (128.0f * NPIX);
    size_t total4 = (size_t)NB * COUT * (NPIX / 4);
    float4* o4 = reinterpret_cast<float4*>(out);
    const float4* s4 = reinterpret_cast<const float4*>(scr);
    for (size_t i = (size_t)blockIdx.x * blockDim.x + threadIdx.x; i < total4;
         i += (size_t)gridDim.x * blockDim.x) {
        size_t flat = i * 4;
        int c = (int)((flat / NPIX) % COUT);
        int b = (int)(flat / ((size_t)COUT * NPIX));
        int bg = b * 4 + (c >> 7);
        float2 p2 = gn_params(st2,  bg, invcnt);
        float2 ps = gn_params(stsc, bg, invcnt);
        float w2 = g2w[c] * p2.y, b2 = g2b[c] - p2.x * p2.y * g2w[c];
        float wsc = gsw[c] * ps.y, bsc = gsb[c] - ps.x * ps.y * gsw[c];
        float4 a = o4[i], r = s4[i], z;
        z.x = fmaxf(a.x * w2 + b2, 0.f) + fmaxf(r.x * wsc + bsc, 0.f);
        z.y = fmaxf(a.y * w2 + b2, 0.f) + fmaxf(r.y * wsc + bsc, 0.f);
        z.z = fmaxf(a.z * w2 + b2, 0.f) + fmaxf(r.z * wsc + bsc, 0.f);
        z.w = fmaxf(a.w * w2 + b2, 0.f) + fmaxf(r.w * wsc + bsc, 0.f);
        o4[i] = z;
    }
}

// ---------------- final gn_out, in place ----------------
__global__ void norm_kernel(float* __restrict__ out, const float* __restrict__ st3,
                            const float* __restrict__ gw, const float* __restrict__ gb)
{
    const float invcnt = 1.0f / (128.0f * NPIX);
    size_t total4 = (size_t)NB * COUT * (NPIX / 4);
    float4* o4 = reinterpret_cast<float4*>(out);
    for (size_t i = (size_t)blockIdx.x * blockDim.x + threadIdx.x; i < total4;
         i += (size_t)gridDim.x * blockDim.x) {
        size_t flat = i * 4;
        int c = (int)((flat / NPIX) % COUT);
        int b = (int)(flat / ((size_t)COUT * NPIX));
        int bg = b * 4 + (c >> 7);
        float2 p = gn_params(st3, bg, invcnt);
        float w_ = gw[c] * p.y, b_ = gb[c] - p.x * p.y * gw[c];
        float4 a = o4[i], z;
        z.x = a.x * w_ + b_; z.y = a.y * w_ + b_; z.z = a.z * w_ + b_; z.w = a.w * w_ + b_;
        o4[i] = z;
    }
}

extern "C" void kernel_launch(void* const* d_in, const int* in_sizes, int n_in,
                              void* d_out, int out_size, void* d_ws, size_t ws_size,
                              hipStream_t stream) {
    (void)in_sizes; (void)n_in; (void)out_size; (void)ws_size;
    const float* corr     = (const float*)d_in[0];
    const int*   smask    = (const int*)  d_in[1];
    const float* W_sc     = (const float*)d_in[2];
    const float* gn_sc_w  = (const float*)d_in[3];
    const float* gn_sc_b  = (const float*)d_in[4];
    const float* W_qkv    = (const float*)d_in[5];
    const float* b_qkv    = (const float*)d_in[6];
    const float* gn1_w    = (const float*)d_in[7];
    const float* gn1_b    = (const float*)d_in[8];
    const float* W_agg    = (const float*)d_in[9];
    const float* gn2_w    = (const float*)d_in[10];
    const float* gn2_b    = (const float*)d_in[11];
    const float* gn_out_w = (const float*)d_in[12];
    const float* gn_out_b = (const float*)d_in[13];
    float* out = (float*)d_out;

    unsigned short* ws = (unsigned short*)d_ws;
    unsigned short* corrT  = ws;                           // 34,603,008 sh
    unsigned short* kbuf   = corrT  + (size_t)34603008;    // 69,206,016 sh
    unsigned short* vbuf   = kbuf   + (size_t)69206016;    // 69,206,016 sh
    unsigned short* corrpT = vbuf   + (size_t)69206016;    //  8,519,680 sh
    unsigned short* qpT    = corrpT + (size_t)8519680;     // 17,047,552 sh (incl pad)
    unsigned short* attT   = qpT    + (size_t)17047552;    // 17,039,360 sh
    unsigned short* wbuf   = attT   + (size_t)17039360;    //    294,912 sh
    float* m16   = (float*)(wbuf + (size_t)294912);        // 1,024 f
    float* stats = m16 + 1024;                             // 128 f
    float* scr   = (float*)d_ws;   // aliases corrT+kbuf head (both dead by then)
    float* st_sc = stats, *st1 = stats + 32, *st2 = stats + 64, *st3 = stats + 96;

    const float inv1 = 1.0f / (64.0f * (float)NPIX);

    hipMemsetAsync(stats, 0, 128 * sizeof(float), stream);
    wprep_kernel<<<dim3(1152), dim3(256), 0, stream>>>(W_qkv, W_sc, W_agg, wbuf);
    mask_kernel<<<dim3(NB), dim3(256), 0, stream>>>(smask, m16);
    tpool_kernel<<<dim3(TQ, 2, NB), dim3(256), 0, stream>>>(corr, corrT, corrpT);
    // Q projection: qpT[b][n][256] = Wq x corrpT + bq
    mgemm_kernel<0,128><<<dim3(130, 2, NB), dim3(256), 0, stream>>>(
        corrpT, wbuf, NPIX, nullptr, qpT, nullptr, nullptr, b_qkv,
        nullptr, nullptr, nullptr, 0.f);
    // K/V projection from corrT
    mgemm_kernel<1,128><<<dim3(528, 4, NB), dim3(256), 0, stream>>>(
        corrT, wbuf + 32768, NPAD, nullptr, nullptr, kbuf, vbuf, b_qkv + 256,
        nullptr, nullptr, nullptr, 0.f);
    attn_kernel<<<dim3(8, TQ, NB), dim3(320), 0, stream>>>(kbuf, vbuf, qpT, m16, attT);
    stats1_kernel<<<dim3(208, NB), dim3(256), 0, stream>>>(attT, st1);
    // agg conv with fused gn1+relu on input: out = W_agg x relu(gn1(attT))
    mgemm_kernel<3,256><<<dim3(130, 4, NB), dim3(256), 0, stream>>>(
        attT, wbuf + 163840, NPIX, out, nullptr, nullptr, nullptr, nullptr,
        st1, gn1_w, gn1_b, inv1);
    stats_kernel<<<dim3(64, 16), dim3(256), 0, stream>>>(out, st2, 128);
    // residual conv: scr = W_sc x corrpT (scr aliases dead corrT/kbuf head)
    mgemm_kernel<2,128><<<dim3(130, 4, NB), dim3(256), 0, stream>>>(
        corrpT, wbuf + 98304, NPIX, scr, nullptr, nullptr, nullptr, nullptr,
        nullptr, nullptr, nullptr, 0.f);
    stats_kernel<<<dim3(64, 16), dim3(256), 0, stream>>>(scr, st_sc, 128);
    z_kernel<<<dim3(4096), dim3(256), 0, stream>>>(out, scr, st2, st_sc, gn2_w, gn2_b, gn_sc_w, gn_sc_b);
    stats_kernel<<<dim3(64, 16), dim3(256), 0, stream>>>(out, st3, 128);
    norm_kernel<<<dim3(4096), dim3(256), 0, stream>>>(out, st3, gn_out_w, gn_out_b);
}